// Round 11
// baseline (7160.260 us; speedup 1.0000x reference)
//
#include <hip/hip_runtime.h>
#include <cstddef>
#include <cstdint>

// Problem dims (fixed)
#define T_   4096
#define IN_  1024
#define E_   512
#define G4_  2048   // 4*E

typedef unsigned short ushort_t;
typedef __attribute__((ext_vector_type(8))) short bf16x8;   // 8 bf16 = 4 VGPRs
typedef __attribute__((ext_vector_type(4))) float f32x4;    // MFMA acc

__device__ __forceinline__ ushort_t rne_bf16(float x) {
    unsigned int u = __float_as_uint(x);
    return (ushort_t)((u + 0x7FFFu + ((u >> 16) & 1u)) >> 16);
}
__device__ __forceinline__ float bf2f(ushort_t h) {
    return __uint_as_float((unsigned int)h << 16);
}

// sc0-only loads: bypass L1, can HIT the local XCD's L2 (agent atomics emit
// sc0+sc1 and go to the MALL instead).
__device__ __forceinline__ unsigned int load_l2_u32(const unsigned int* p) {
    unsigned int v;
    asm volatile("global_load_dword %0, %1, off sc0\n\ts_waitcnt vmcnt(0)"
                 : "=v"(v) : "v"(p) : "memory");
    return v;
}
// FOUR 8B loads in flight concurrently, ONE waitcnt: poll iteration costs
// ~1 L2 RT (v10's per-load waitcnt serialized them into ~4 RT -- the bug
// that ate the barrier-removal win).
__device__ __forceinline__ void load_l2_u64x4(const unsigned long long* p,
    unsigned long long& a, unsigned long long& b,
    unsigned long long& c, unsigned long long& d)
{
    asm volatile(
        "global_load_dwordx2 %0, %4, off sc0\n\t"
        "global_load_dwordx2 %1, %5, off sc0\n\t"
        "global_load_dwordx2 %2, %6, off sc0\n\t"
        "global_load_dwordx2 %3, %7, off sc0\n\t"
        "s_waitcnt vmcnt(0)"
        : "=&v"(a), "=&v"(b), "=&v"(c), "=&v"(d)
        : "v"(p), "v"(p + 64), "v"(p + 128), "v"(p + 192)
        : "memory");
}

__device__ __forceinline__ bool tags8(unsigned long long a, unsigned long long b,
                                      unsigned long long c, unsigned long long d,
                                      unsigned int tt) {
    return ((unsigned int)a >> 16) == tt && (unsigned int)(a >> 48) == tt &&
           ((unsigned int)b >> 16) == tt && (unsigned int)(b >> 48) == tt &&
           ((unsigned int)c >> 16) == tt && (unsigned int)(c >> 48) == tt &&
           ((unsigned int)d >> 16) == tt && (unsigned int)(d >> 48) == tt;
}

// ---------------------------------------------------------------------------
// Split-bf16 MFMA GEMM (unchanged from round 8).
// ---------------------------------------------------------------------------
__global__ __launch_bounds__(256) void mfma_gemm(
    const ushort_t* __restrict__ Ah, const ushort_t* __restrict__ Al,
    const ushort_t* __restrict__ Bh, const ushort_t* __restrict__ Bl,
    float* __restrict__ Cf, ushort_t* __restrict__ Ch, ushort_t* __restrict__ Cl,
    int M, int N, int K, int nA,
    const float* __restrict__ bias1, const float* __restrict__ bias2)
{
    __shared__ ushort_t sAh[128 * 40], sAl[128 * 40];
    __shared__ ushort_t sBh[128 * 40], sBl[128 * 40];

    const int tid  = threadIdx.x;
    const int wv   = tid >> 6;
    const int lane = tid & 63;
    const int quad = lane >> 4;
    const int l16  = lane & 15;
    const int bm = blockIdx.y * 128, bn = blockIdx.x * 128;
    const int wrow = (wv & 1) * 64, wcol = (wv >> 1) * 64;

    f32x4 acc[4][4];
#pragma unroll
    for (int i = 0; i < 4; ++i)
#pragma unroll
        for (int j = 0; j < 4; ++j) acc[i][j] = (f32x4){0.f, 0.f, 0.f, 0.f};

    const int r0 = tid >> 2;
    const int ks = (tid & 3) * 8;

    for (int k0 = 0; k0 < K; k0 += 32) {
        const size_t ga0 = (size_t)(bm + r0) * K + k0 + ks;
        const size_t ga1 = (size_t)(bm + r0 + 64) * K + k0 + ks;
        const size_t gb0 = (size_t)(bn + r0) * K + k0 + ks;
        const size_t gb1 = (size_t)(bn + r0 + 64) * K + k0 + ks;
        uint4 vA0 = *(const uint4*)(Ah + ga0);
        uint4 vA1 = *(const uint4*)(Ah + ga1);
        uint4 vB0h = *(const uint4*)(Bh + gb0);
        uint4 vB1h = *(const uint4*)(Bh + gb1);
        uint4 vB0l = *(const uint4*)(Bl + gb0);
        uint4 vB1l = *(const uint4*)(Bl + gb1);
        uint4 vA0l, vA1l;
        if (nA == 2) { vA0l = *(const uint4*)(Al + ga0); vA1l = *(const uint4*)(Al + ga1); }
        __syncthreads();
        *(uint4*)&sAh[r0 * 40 + ks] = vA0;
        *(uint4*)&sAh[(r0 + 64) * 40 + ks] = vA1;
        *(uint4*)&sBh[r0 * 40 + ks] = vB0h;
        *(uint4*)&sBh[(r0 + 64) * 40 + ks] = vB1h;
        *(uint4*)&sBl[r0 * 40 + ks] = vB0l;
        *(uint4*)&sBl[(r0 + 64) * 40 + ks] = vB1l;
        if (nA == 2) {
            *(uint4*)&sAl[r0 * 40 + ks] = vA0l;
            *(uint4*)&sAl[(r0 + 64) * 40 + ks] = vA1l;
        }
        __syncthreads();

        bf16x8 afh[4], afl[4], bfh[4], bfl[4];
#pragma unroll
        for (int f = 0; f < 4; ++f) {
            const int ar = (wrow + f * 16 + l16) * 40 + quad * 8;
            const int br = (wcol + f * 16 + l16) * 40 + quad * 8;
            afh[f] = *(const bf16x8*)&sAh[ar];
            bfh[f] = *(const bf16x8*)&sBh[br];
            bfl[f] = *(const bf16x8*)&sBl[br];
            if (nA == 2) afl[f] = *(const bf16x8*)&sAl[ar];
        }
#pragma unroll
        for (int fi = 0; fi < 4; ++fi)
#pragma unroll
            for (int fj = 0; fj < 4; ++fj) {
                acc[fi][fj] = __builtin_amdgcn_mfma_f32_16x16x32_bf16(
                    afh[fi], bfh[fj], acc[fi][fj], 0, 0, 0);
                acc[fi][fj] = __builtin_amdgcn_mfma_f32_16x16x32_bf16(
                    afh[fi], bfl[fj], acc[fi][fj], 0, 0, 0);
                if (nA == 2)
                    acc[fi][fj] = __builtin_amdgcn_mfma_f32_16x16x32_bf16(
                        afl[fi], bfh[fj], acc[fi][fj], 0, 0, 0);
            }
    }

#pragma unroll
    for (int fi = 0; fi < 4; ++fi)
#pragma unroll
        for (int fj = 0; fj < 4; ++fj) {
            const int col = bn + wcol + fj * 16 + l16;
            float bv = 0.f;
            if (bias1) bv += bias1[col];
            if (bias2) bv += bias2[col];
#pragma unroll
            for (int r = 0; r < 4; ++r) {
                const int row = bm + wrow + fi * 16 + quad * 4 + r;
                const float v = acc[fi][fj][r] + bv;
                const size_t o = (size_t)row * N + col;
                if (Cf) Cf[o] = v;
                if (Ch) {
                    const ushort_t h = rne_bf16(v);
                    Ch[o] = h;
                    if (Cl) Cl[o] = rne_bf16(v - bf2f(h));
                }
            }
        }
}

// fp32 -> (hi, lo) bf16 split, elementwise
__global__ __launch_bounds__(256) void conv_hl(
    const float* __restrict__ in, ushort_t* __restrict__ oh, ushort_t* __restrict__ ol)
{
    const size_t i = ((size_t)blockIdx.x * 256 + threadIdx.x) * 4;
    float4 v = *(const float4*)(in + i);
    ushort4 h, l;
    h.x = rne_bf16(v.x); l.x = rne_bf16(v.x - bf2f(h.x));
    h.y = rne_bf16(v.y); l.y = rne_bf16(v.y - bf2f(h.y));
    h.z = rne_bf16(v.z); l.z = rne_bf16(v.z - bf2f(h.z));
    h.w = rne_bf16(v.w); l.w = rne_bf16(v.w - bf2f(h.w));
    *(ushort4*)(oh + i) = h;
    *(ushort4*)(ol + i) = l;
}

// fp32 [R][C] -> transposed (hi, lo) bf16 [C][R]
__global__ __launch_bounds__(256) void conv_hl_T(
    const float* __restrict__ in, ushort_t* __restrict__ oh, ushort_t* __restrict__ ol,
    int R, int C)
{
    __shared__ float t[32][33];
    const int tx = threadIdx.x & 31, ty = threadIdx.x >> 5;  // 32x8
    const int gr = blockIdx.y * 32, gc = blockIdx.x * 32;
#pragma unroll
    for (int i = 0; i < 4; ++i)
        t[ty + 8 * i][tx] = in[(size_t)(gr + ty + 8 * i) * C + gc + tx];
    __syncthreads();
#pragma unroll
    for (int i = 0; i < 4; ++i) {
        const int oc = gc + ty + 8 * i;
        const float v = t[tx][ty + 8 * i];
        const ushort_t h = rne_bf16(v);
        oh[(size_t)oc * R + gr + tx] = h;
        ol[(size_t)oc * R + gr + tx] = rne_bf16(v - bf2f(h));
    }
}

// Row softmax over 4096 cols; fp32 in, bf16 out.
__global__ __launch_bounds__(256) void softmax_kernel(
    const float* __restrict__ S, ushort_t* __restrict__ P)
{
    __shared__ float red[8];
    const float* p = S + (size_t)blockIdx.x * T_;
    ushort_t* pr = P + (size_t)blockIdx.x * T_;
    const int tid = threadIdx.x;
    const int wid = tid >> 6;
    const int lane = tid & 63;
    float4 v[4];
#pragma unroll
    for (int i = 0; i < 4; ++i) v[i] = ((const float4*)p)[tid + 256 * i];
    float m = -3.0e38f;
#pragma unroll
    for (int i = 0; i < 4; ++i)
        m = fmaxf(m, fmaxf(fmaxf(v[i].x, v[i].y), fmaxf(v[i].z, v[i].w)));
#pragma unroll
    for (int o = 32; o; o >>= 1) m = fmaxf(m, __shfl_xor(m, o));
    if (lane == 0) red[wid] = m;
    __syncthreads();
    m = fmaxf(fmaxf(red[0], red[1]), fmaxf(red[2], red[3]));
    float s = 0.f;
#pragma unroll
    for (int i = 0; i < 4; ++i) {
        v[i].x = __expf(v[i].x - m); v[i].y = __expf(v[i].y - m);
        v[i].z = __expf(v[i].z - m); v[i].w = __expf(v[i].w - m);
        s += v[i].x + v[i].y + v[i].z + v[i].w;
    }
#pragma unroll
    for (int o = 32; o; o >>= 1) s += __shfl_xor(s, o);
    if (lane == 0) red[4 + wid] = s;
    __syncthreads();
    s = red[4] + red[5] + red[6] + red[7];
    const float inv = 1.f / s;
#pragma unroll
    for (int i = 0; i < 4; ++i) {
        ushort4 o4;
        o4.x = rne_bf16(v[i].x * inv); o4.y = rne_bf16(v[i].y * inv);
        o4.z = rne_bf16(v[i].z * inv); o4.w = rne_bf16(v[i].w * inv);
        ((ushort4*)pr)[tid + 256 * i] = o4;
    }
}

// um = (uh+ul) * ov, output as h/l split
__global__ __launch_bounds__(256) void umod_kernel(
    const ushort_t* __restrict__ uh, const ushort_t* __restrict__ ul,
    const float* __restrict__ ov,
    ushort_t* __restrict__ mh, ushort_t* __restrict__ ml)
{
    const size_t i = ((size_t)blockIdx.x * 256 + threadIdx.x) * 4;
    ushort4 h4 = *(const ushort4*)(uh + i);
    ushort4 l4 = *(const ushort4*)(ul + i);
    float4 o = *(const float4*)(ov + i);
    float4 m;
    m.x = (bf2f(h4.x) + bf2f(l4.x)) * o.x;
    m.y = (bf2f(h4.y) + bf2f(l4.y)) * o.y;
    m.z = (bf2f(h4.z) + bf2f(l4.z)) * o.z;
    m.w = (bf2f(h4.w) + bf2f(l4.w)) * o.w;
    ushort4 oh, ol;
    oh.x = rne_bf16(m.x); ol.x = rne_bf16(m.x - bf2f(oh.x));
    oh.y = rne_bf16(m.y); ol.y = rne_bf16(m.y - bf2f(oh.y));
    oh.z = rne_bf16(m.z); ol.z = rne_bf16(m.z - bf2f(oh.z));
    oh.w = rne_bf16(m.w); ol.w = rne_bf16(m.w - bf2f(oh.w));
    *(ushort4*)(mh + i) = oh;
    *(ushort4*)(ml + i) = ol;
}

// ---------------------------------------------------------------------------
// Persistent bidirectional LSTM, v11 = v10 with the poll de-serialized:
// the 4 per-lane 8B sc0 loads issue back-to-back under ONE s_waitcnt
// (load_l2_u64x4), so a poll iteration costs ~1 L2 RT, not 4.
// All else identical to v10: one-time mapping consensus -> local-only
// publish; barrier-free steps with per-wave private LDS h-stage; tagged
// 2-parity dataflow; pace 8 (local) / 25 (agent fallback).
// ---------------------------------------------------------------------------
#define NU_ 16
#define PACE_L 8L
#define PACE_A 25L

__global__ __launch_bounds__(256, 1) void lstm_kernel(
    const float* __restrict__ whh_f, const float* __restrict__ whh_b,
    const ushort_t* __restrict__ xg_f, const ushort_t* __restrict__ xg_b,
    float* __restrict__ hf_out, float* __restrict__ hb_out,
    unsigned int* __restrict__ hbuf,   // agent/MALL: [2 dirs][2 parity][512]
    unsigned int* __restrict__ lbuf,   // XCD-local:  [2 dirs][2 parity][512]
    unsigned int* __restrict__ pbuf,   // probes  [2][32] (local)
    unsigned int* __restrict__ vbuf)   // verdicts [2][32] (agent)
{
    const int xcd = blockIdx.x & 7;
    if (xcd >= 2) return;               // helper blocks exit
    const int dir = xcd;
    const int w   = blockIdx.x >> 3;    // 0..31

    __shared__ float sh[4][2][528];     // per-wave private, parity-dbuffered
    __shared__ int smode;

    const int tid  = threadIdx.x;
    const int wv   = tid >> 6;
    const int lane = tid & 63;
    const int j    = tid >> 4;
    const int g    = (tid >> 2) & 3;
    const int c    = tid & 3;
    const int lu   = lane >> 4;
    const int u0   = w * NU_;

    const float* whh = dir ? whh_b : whh_f;
    const ushort_t* xg = dir ? xg_b : xg_f;
    float* hout = dir ? hb_out : hf_out;
    unsigned int* hb = hbuf + dir * 1024;
    unsigned int* lb = lbuf + dir * 1024;

    float wreg[128];
    {
        const float* wr = whh + (size_t)(g * E_ + u0 + j) * E_ + 128 * c;
#pragma unroll
        for (int i = 0; i < 32; ++i)
            *(float4*)&wreg[4 * i] = *(const float4*)(wr + 4 * i);
    }
    for (int i = tid; i < 4 * 2 * 528; i += 256) ((float*)sh)[i] = 0.f;

    // ---- one-time mapping consensus ----
    if (tid == 0)
        __hip_atomic_store(pbuf + dir * 32 + w, 0x5AFE0001u,
                           __ATOMIC_RELAXED, __HIP_MEMORY_SCOPE_WORKGROUP);
    if (tid < 64) {
        bool seen = true;
        if (lane < 32) {
            seen = false;
            const long long t0 = (long long)__builtin_amdgcn_s_memrealtime();
            while (!seen) {
                seen = (load_l2_u32(pbuf + dir * 32 + lane) == 0x5AFE0001u);
                if (!seen &&
                    (long long)__builtin_amdgcn_s_memrealtime() - t0 > 1000) break;
            }
        }
        const int allok = (__ballot(seen) == ~0ull) ? 1 : 0;
        if (lane == 0)
            __hip_atomic_store(vbuf + dir * 32 + w, 0x7E570000u | (unsigned)allok,
                               __ATOMIC_RELAXED, __HIP_MEMORY_SCOPE_AGENT);
        bool vok = true;
        if (lane < 32) {
            unsigned int vv = 0, vb = 1u << 22;
            for (;;) {
                vv = __hip_atomic_load(vbuf + dir * 32 + lane, __ATOMIC_RELAXED,
                                       __HIP_MEMORY_SCOPE_AGENT);
                if ((vv >> 16) == 0x7E57u || !--vb) break;
            }
            vok = ((vv >> 16) == 0x7E57u) && (vv & 1u);
        }
        const int consensus = (__ballot(vok) == ~0ull) ? 1 : 0;
        if (lane == 0 && wv == 0) smode = consensus;
    }
    __syncthreads();                    // one-time: smode + sh zero-init
    const int mode_local = smode;

    float creg = 0.f;
    const float gsc  = (g == 2) ? 2.f : 1.f;
    const float gmul = (g == 2) ? 2.f : 1.f;
    const float gadd = (g == 2) ? -1.f : 0.f;

    float xv = bf2f(xg[(size_t)(dir ? (T_ - 1) : 0) * G4_ + g * E_ + u0 + j]);
    unsigned int budget = 1u << 23;

    long long tpub = (long long)__builtin_amdgcn_s_memrealtime();

    for (int s = 0; s < T_; ++s) {
        const int t = dir ? (T_ - 1 - s) : s;
        float* shw = sh[wv][s & 1];

        if (s > 0) {
            const long long pt = mode_local ? PACE_L : PACE_A;
            while ((long long)__builtin_amdgcn_s_memrealtime() - tpub < pt) {}
            const unsigned int tt = (unsigned int)(s - 1) & 0xFFFFu;
            const unsigned long long* src = (const unsigned long long*)
                ((mode_local ? lb : hb) + ((s - 1) & 1) * 512);
            unsigned long long v0, v1, v2, v3;
            if (mode_local) {
                for (;;) {
                    load_l2_u64x4(src + lane, v0, v1, v2, v3);
                    if (tags8(v0, v1, v2, v3, tt) || !--budget) break;
                }
            } else {
                for (;;) {
                    v0 = __hip_atomic_load(src + lane, __ATOMIC_RELAXED,
                                           __HIP_MEMORY_SCOPE_AGENT);
                    v1 = __hip_atomic_load(src + lane + 64, __ATOMIC_RELAXED,
                                           __HIP_MEMORY_SCOPE_AGENT);
                    v2 = __hip_atomic_load(src + lane + 128, __ATOMIC_RELAXED,
                                           __HIP_MEMORY_SCOPE_AGENT);
                    v3 = __hip_atomic_load(src + lane + 192, __ATOMIC_RELAXED,
                                           __HIP_MEMORY_SCOPE_AGENT);
                    if (tags8(v0, v1, v2, v3, tt) || !--budget) break;
                }
            }
            // stage into THIS wave's private buffer: u64 m=lane+64i holds
            // h units e=2m, 2m+1 -> chunk i, offset 2*lane (b64, 2-way free)
            float2 h0, h1, h2, h3;
            h0.x = __uint_as_float((unsigned int)v0 << 16);
            h0.y = __uint_as_float((unsigned int)(v0 >> 32) << 16);
            h1.x = __uint_as_float((unsigned int)v1 << 16);
            h1.y = __uint_as_float((unsigned int)(v1 >> 32) << 16);
            h2.x = __uint_as_float((unsigned int)v2 << 16);
            h2.y = __uint_as_float((unsigned int)(v2 >> 32) << 16);
            h3.x = __uint_as_float((unsigned int)v3 << 16);
            h3.y = __uint_as_float((unsigned int)(v3 >> 32) << 16);
            *(float2*)&shw[2 * lane]           = h0;
            *(float2*)&shw[132 + 2 * lane]     = h1;
            *(float2*)&shw[264 + 2 * lane]     = h2;
            *(float2*)&shw[396 + 2 * lane]     = h3;
            asm volatile("s_waitcnt lgkmcnt(0)" ::: "memory");  // intra-wave order
        }

        const float* hc = &shw[132 * c];
        float sx = 0.f, sy = 0.f, sz = 0.f, sw = 0.f;
#pragma unroll
        for (int i = 0; i < 32; ++i) {
            const float4 h4 = *(const float4*)&hc[4 * i];
            sx = fmaf(wreg[4 * i + 0], h4.x, sx);
            sy = fmaf(wreg[4 * i + 1], h4.y, sy);
            sz = fmaf(wreg[4 * i + 2], h4.z, sz);
            sw = fmaf(wreg[4 * i + 3], h4.w, sw);
        }
        float sum = (sx + sy) + (sz + sw);
        sum += __shfl_xor(sum, 1);
        sum += __shfl_xor(sum, 2);

        const float xx = (sum + xv) * gsc;
        const float rr = __builtin_amdgcn_rcpf(1.f + __expf(-xx));
        const float val = fmaf(rr, gmul, gadd);

        const int base = 16 * lu + c;
        const float iv = __shfl(val, base);
        const float fv = __shfl(val, base + 4);
        const float gv = __shfl(val, base + 8);
        const float ov = __shfl(val, base + 12);
        creg = fmaf(fv, creg, iv * gv);
        const float th = fmaf(2.f, __builtin_amdgcn_rcpf(1.f + __expf(-2.f * creg)), -1.f);
        const float h = ov * th;

        if ((tid & 15) == 0) {
            const unsigned int ub = __float_as_uint(h);
            const unsigned int b16 = (ub + 0x7FFFu + ((ub >> 16) & 1u)) >> 16;
            const unsigned int pkt = (((unsigned int)s & 0xFFFFu) << 16) | b16;
            if (mode_local) {
                __hip_atomic_store(lb + (s & 1) * 512 + u0 + j, pkt,
                                   __ATOMIC_RELAXED, __HIP_MEMORY_SCOPE_WORKGROUP);
            } else {
                __hip_atomic_store(hb + (s & 1) * 512 + u0 + j, pkt,
                                   __ATOMIC_RELAXED, __HIP_MEMORY_SCOPE_AGENT);
            }
            hout[(size_t)t * E_ + u0 + j] = h;
        }
        tpub = (long long)__builtin_amdgcn_s_memrealtime();

        if (s + 1 < T_)
            xv = bf2f(xg[(size_t)(dir ? (T_ - 2 - s) : (s + 1)) * G4_ + g * E_ + u0 + j]);
    }
}

// score[t] = dot(hf[t], fw[0:512]) + dot(hb[t], fw[512:1024]) + fb
__global__ __launch_bounds__(256) void final_kernel(
    const float* __restrict__ hf, const float* __restrict__ hb,
    const float* __restrict__ fw, const float* __restrict__ fb,
    float* __restrict__ out)
{
    const int t = blockIdx.x * 4 + (threadIdx.x >> 6);
    const int lane = threadIdx.x & 63;
    float s = 0.f;
#pragma unroll
    for (int i = 0; i < 8; ++i) {
        const int e = lane + 64 * i;
        s += hf[(size_t)t * E_ + e] * fw[e];
    }
#pragma unroll
    for (int i = 0; i < 8; ++i) {
        const int e = lane + 64 * i;
        s += hb[(size_t)t * E_ + e] * fw[E_ + e];
    }
#pragma unroll
    for (int o = 32; o; o >>= 1) s += __shfl_xor(s, o);
    if (lane == 0) out[t] = s + fb[0];
}

// ---------------------------------------------------------------------------
// Workspace layout (MiB offsets; peak ~114 MiB):
//  uh@0-4 ul@4-8 | b@8-16 | xh@16-24 xl@24-32 | ATh@32 ATl@33 BTh@34 BTl@35
//  UTh@36 UTl@37 | ah@38-42 al@42-46 | bTh@46-50 bTl@50-54 | S@56-120
//  Ph@8-40 | ov@56-64 umh@64-68 uml@68-72 wfh@72 wfl@74 wbh@76 wbl@78
//  xfg@80-96 xbg@96-112 | hf@0-8 hb@8-16
//  hbuf@112 lbuf@112+8K pbuf@112+16K vbuf@112+20K
// ---------------------------------------------------------------------------
extern "C" void kernel_launch(void* const* d_in, const int* in_sizes, int n_in,
                              void* d_out, int out_size, void* d_ws, size_t ws_size,
                              hipStream_t stream)
{
    const float* x     = (const float*)d_in[0];
    const float* Amat  = (const float*)d_in[1];
    const float* Bmat  = (const float*)d_in[2];
    const float* Umat  = (const float*)d_in[3];
    const float* wih_f = (const float*)d_in[4];
    const float* whh_f = (const float*)d_in[5];
    const float* bih_f = (const float*)d_in[6];
    const float* bhh_f = (const float*)d_in[7];
    const float* wih_b = (const float*)d_in[8];
    const float* whh_b = (const float*)d_in[9];
    const float* bih_b = (const float*)d_in[10];
    const float* bhh_b = (const float*)d_in[11];
    const float* fw    = (const float*)d_in[12];
    const float* fb    = (const float*)d_in[13];
    float* out = (float*)d_out;
    char* wsb = (char*)d_ws;
    const size_t MB = 1048576ull;

    ushort_t* uh  = (ushort_t*)(wsb + 0 * MB);
    ushort_t* ul  = (ushort_t*)(wsb + 4 * MB);
    float*    bfp = (float*)   (wsb + 8 * MB);
    ushort_t* xh  = (ushort_t*)(wsb + 16 * MB);
    ushort_t* xl  = (ushort_t*)(wsb + 24 * MB);
    ushort_t* ATh = (ushort_t*)(wsb + 32 * MB);
    ushort_t* ATl = (ushort_t*)(wsb + 33 * MB);
    ushort_t* BTh = (ushort_t*)(wsb + 34 * MB);
    ushort_t* BTl = (ushort_t*)(wsb + 35 * MB);
    ushort_t* UTh = (ushort_t*)(wsb + 36 * MB);
    ushort_t* UTl = (ushort_t*)(wsb + 37 * MB);
    ushort_t* ah  = (ushort_t*)(wsb + 38 * MB);
    ushort_t* al  = (ushort_t*)(wsb + 42 * MB);
    ushort_t* bTh = (ushort_t*)(wsb + 46 * MB);
    ushort_t* bTl = (ushort_t*)(wsb + 50 * MB);
    float*    S_  = (float*)   (wsb + 56 * MB);
    ushort_t* Ph  = (ushort_t*)(wsb + 8 * MB);
    float*    ov_ = (float*)   (wsb + 56 * MB);
    ushort_t* umh = (ushort_t*)(wsb + 64 * MB);
    ushort_t* uml = (ushort_t*)(wsb + 68 * MB);
    ushort_t* wfh = (ushort_t*)(wsb + 72 * MB);
    ushort_t* wfl = (ushort_t*)(wsb + 74 * MB);
    ushort_t* wbh = (ushort_t*)(wsb + 76 * MB);
    ushort_t* wbl = (ushort_t*)(wsb + 78 * MB);
    ushort_t* xfg = (ushort_t*)(wsb + 80 * MB);
    ushort_t* xbg = (ushort_t*)(wsb + 96 * MB);
    float*    hf_ = (float*)   (wsb + 0 * MB);
    float*    hb_ = (float*)   (wsb + 8 * MB);
    unsigned int* hbuf_ = (unsigned int*)(wsb + 112 * MB);
    unsigned int* lbuf_ = (unsigned int*)(wsb + 112 * MB + 8192);
    unsigned int* pbuf_ = (unsigned int*)(wsb + 112 * MB + 16384);
    unsigned int* vbuf_ = (unsigned int*)(wsb + 112 * MB + 20480);

    dim3 blk(256);

    conv_hl<<<dim3(4096), blk, 0, stream>>>(x, xh, xl);
    conv_hl_T<<<dim3(16, 32), blk, 0, stream>>>(Amat, ATh, ATl, 1024, 512);
    conv_hl_T<<<dim3(16, 32), blk, 0, stream>>>(Bmat, BTh, BTl, 1024, 512);
    conv_hl_T<<<dim3(16, 32), blk, 0, stream>>>(Umat, UTh, UTl, 1024, 512);
    mfma_gemm<<<dim3(4, 32), blk, 0, stream>>>(xh, xl, ATh, ATl, nullptr, ah, al,
                                               T_, E_, IN_, 2, nullptr, nullptr);
    mfma_gemm<<<dim3(4, 32), blk, 0, stream>>>(xh, xl, BTh, BTl, bfp, nullptr, nullptr,
                                               T_, E_, IN_, 2, nullptr, nullptr);
    mfma_gemm<<<dim3(4, 32), blk, 0, stream>>>(xh, xl, UTh, UTl, nullptr, uh, ul,
                                               T_, E_, IN_, 2, nullptr, nullptr);
    mfma_gemm<<<dim3(32, 32), blk, 0, stream>>>(uh, ul, ah, al, S_, nullptr, nullptr,
                                                T_, T_, E_, 2, nullptr, nullptr);
    conv_hl_T<<<dim3(16, 128), blk, 0, stream>>>(bfp, bTh, bTl, 4096, 512);
    softmax_kernel<<<dim3(T_), blk, 0, stream>>>(S_, Ph);
    mfma_gemm<<<dim3(4, 32), blk, 0, stream>>>(Ph, nullptr, bTh, bTl, ov_, nullptr, nullptr,
                                               T_, E_, T_, 1, nullptr, nullptr);
    umod_kernel<<<dim3(2048), blk, 0, stream>>>(uh, ul, ov_, umh, uml);
    conv_hl<<<dim3(1024), blk, 0, stream>>>(wih_f, wfh, wfl);
    conv_hl<<<dim3(1024), blk, 0, stream>>>(wih_b, wbh, wbl);
    mfma_gemm<<<dim3(16, 32), blk, 0, stream>>>(umh, uml, wfh, wfl, nullptr, xfg, nullptr,
                                                T_, G4_, E_, 2, bih_f, bhh_f);
    mfma_gemm<<<dim3(16, 32), blk, 0, stream>>>(umh, uml, wbh, wbl, nullptr, xbg, nullptr,
                                                T_, G4_, E_, 2, bih_b, bhh_b);
    lstm_kernel<<<dim3(256), blk, 0, stream>>>(whh_f, whh_b, xfg, xbg, hf_, hb_,
                                               hbuf_, lbuf_, pbuf_, vbuf_);
    final_kernel<<<dim3(1024), blk, 0, stream>>>(hf_, hb_, fw, fb, out);
}

// Round 12
// 6365.871 us; speedup vs baseline: 1.1248x; 1.1248x over previous
//
#include <hip/hip_runtime.h>
#include <cstddef>
#include <cstdint>

// Problem dims (fixed)
#define T_   4096
#define IN_  1024
#define E_   512
#define G4_  2048   // 4*E

typedef unsigned short ushort_t;
typedef __attribute__((ext_vector_type(8))) short bf16x8;   // 8 bf16 = 4 VGPRs
typedef __attribute__((ext_vector_type(4))) float f32x4;    // MFMA acc

__device__ __forceinline__ ushort_t rne_bf16(float x) {
    unsigned int u = __float_as_uint(x);
    return (ushort_t)((u + 0x7FFFu + ((u >> 16) & 1u)) >> 16);
}
__device__ __forceinline__ float bf2f(ushort_t h) {
    return __uint_as_float((unsigned int)h << 16);
}

// sc0-only loads: bypass L1, can HIT the local XCD's L2 (agent atomics emit
// sc0+sc1 and go to the MALL instead).
__device__ __forceinline__ unsigned int load_l2_u32(const unsigned int* p) {
    unsigned int v;
    asm volatile("global_load_dword %0, %1, off sc0\n\ts_waitcnt vmcnt(0)"
                 : "=v"(v) : "v"(p) : "memory");
    return v;
}
// FOUR 8B loads in flight concurrently, ONE waitcnt: poll iteration ~1 L2 RT.
__device__ __forceinline__ void load_l2_u64x4(const unsigned long long* p,
    unsigned long long& a, unsigned long long& b,
    unsigned long long& c, unsigned long long& d)
{
    asm volatile(
        "global_load_dwordx2 %0, %4, off sc0\n\t"
        "global_load_dwordx2 %1, %5, off sc0\n\t"
        "global_load_dwordx2 %2, %6, off sc0\n\t"
        "global_load_dwordx2 %3, %7, off sc0\n\t"
        "s_waitcnt vmcnt(0)"
        : "=&v"(a), "=&v"(b), "=&v"(c), "=&v"(d)
        : "v"(p), "v"(p + 64), "v"(p + 128), "v"(p + 192)
        : "memory");
}

__device__ __forceinline__ bool tags8(unsigned long long a, unsigned long long b,
                                      unsigned long long c, unsigned long long d,
                                      unsigned int tt) {
    return ((unsigned int)a >> 16) == tt && (unsigned int)(a >> 48) == tt &&
           ((unsigned int)b >> 16) == tt && (unsigned int)(b >> 48) == tt &&
           ((unsigned int)c >> 16) == tt && (unsigned int)(c >> 48) == tt &&
           ((unsigned int)d >> 16) == tt && (unsigned int)(d >> 48) == tt;
}

// ---------------------------------------------------------------------------
// Split-bf16 MFMA GEMM (unchanged from round 8).
// ---------------------------------------------------------------------------
__global__ __launch_bounds__(256) void mfma_gemm(
    const ushort_t* __restrict__ Ah, const ushort_t* __restrict__ Al,
    const ushort_t* __restrict__ Bh, const ushort_t* __restrict__ Bl,
    float* __restrict__ Cf, ushort_t* __restrict__ Ch, ushort_t* __restrict__ Cl,
    int M, int N, int K, int nA,
    const float* __restrict__ bias1, const float* __restrict__ bias2)
{
    __shared__ ushort_t sAh[128 * 40], sAl[128 * 40];
    __shared__ ushort_t sBh[128 * 40], sBl[128 * 40];

    const int tid  = threadIdx.x;
    const int wv   = tid >> 6;
    const int lane = tid & 63;
    const int quad = lane >> 4;
    const int l16  = lane & 15;
    const int bm = blockIdx.y * 128, bn = blockIdx.x * 128;
    const int wrow = (wv & 1) * 64, wcol = (wv >> 1) * 64;

    f32x4 acc[4][4];
#pragma unroll
    for (int i = 0; i < 4; ++i)
#pragma unroll
        for (int j = 0; j < 4; ++j) acc[i][j] = (f32x4){0.f, 0.f, 0.f, 0.f};

    const int r0 = tid >> 2;
    const int ks = (tid & 3) * 8;

    for (int k0 = 0; k0 < K; k0 += 32) {
        const size_t ga0 = (size_t)(bm + r0) * K + k0 + ks;
        const size_t ga1 = (size_t)(bm + r0 + 64) * K + k0 + ks;
        const size_t gb0 = (size_t)(bn + r0) * K + k0 + ks;
        const size_t gb1 = (size_t)(bn + r0 + 64) * K + k0 + ks;
        uint4 vA0 = *(const uint4*)(Ah + ga0);
        uint4 vA1 = *(const uint4*)(Ah + ga1);
        uint4 vB0h = *(const uint4*)(Bh + gb0);
        uint4 vB1h = *(const uint4*)(Bh + gb1);
        uint4 vB0l = *(const uint4*)(Bl + gb0);
        uint4 vB1l = *(const uint4*)(Bl + gb1);
        uint4 vA0l, vA1l;
        if (nA == 2) { vA0l = *(const uint4*)(Al + ga0); vA1l = *(const uint4*)(Al + ga1); }
        __syncthreads();
        *(uint4*)&sAh[r0 * 40 + ks] = vA0;
        *(uint4*)&sAh[(r0 + 64) * 40 + ks] = vA1;
        *(uint4*)&sBh[r0 * 40 + ks] = vB0h;
        *(uint4*)&sBh[(r0 + 64) * 40 + ks] = vB1h;
        *(uint4*)&sBl[r0 * 40 + ks] = vB0l;
        *(uint4*)&sBl[(r0 + 64) * 40 + ks] = vB1l;
        if (nA == 2) {
            *(uint4*)&sAl[r0 * 40 + ks] = vA0l;
            *(uint4*)&sAl[(r0 + 64) * 40 + ks] = vA1l;
        }
        __syncthreads();

        bf16x8 afh[4], afl[4], bfh[4], bfl[4];
#pragma unroll
        for (int f = 0; f < 4; ++f) {
            const int ar = (wrow + f * 16 + l16) * 40 + quad * 8;
            const int br = (wcol + f * 16 + l16) * 40 + quad * 8;
            afh[f] = *(const bf16x8*)&sAh[ar];
            bfh[f] = *(const bf16x8*)&sBh[br];
            bfl[f] = *(const bf16x8*)&sBl[br];
            if (nA == 2) afl[f] = *(const bf16x8*)&sAl[ar];
        }
#pragma unroll
        for (int fi = 0; fi < 4; ++fi)
#pragma unroll
            for (int fj = 0; fj < 4; ++fj) {
                acc[fi][fj] = __builtin_amdgcn_mfma_f32_16x16x32_bf16(
                    afh[fi], bfh[fj], acc[fi][fj], 0, 0, 0);
                acc[fi][fj] = __builtin_amdgcn_mfma_f32_16x16x32_bf16(
                    afh[fi], bfl[fj], acc[fi][fj], 0, 0, 0);
                if (nA == 2)
                    acc[fi][fj] = __builtin_amdgcn_mfma_f32_16x16x32_bf16(
                        afl[fi], bfh[fj], acc[fi][fj], 0, 0, 0);
            }
    }

#pragma unroll
    for (int fi = 0; fi < 4; ++fi)
#pragma unroll
        for (int fj = 0; fj < 4; ++fj) {
            const int col = bn + wcol + fj * 16 + l16;
            float bv = 0.f;
            if (bias1) bv += bias1[col];
            if (bias2) bv += bias2[col];
#pragma unroll
            for (int r = 0; r < 4; ++r) {
                const int row = bm + wrow + fi * 16 + quad * 4 + r;
                const float v = acc[fi][fj][r] + bv;
                const size_t o = (size_t)row * N + col;
                if (Cf) Cf[o] = v;
                if (Ch) {
                    const ushort_t h = rne_bf16(v);
                    Ch[o] = h;
                    if (Cl) Cl[o] = rne_bf16(v - bf2f(h));
                }
            }
        }
}

// fp32 -> (hi, lo) bf16 split, elementwise
__global__ __launch_bounds__(256) void conv_hl(
    const float* __restrict__ in, ushort_t* __restrict__ oh, ushort_t* __restrict__ ol)
{
    const size_t i = ((size_t)blockIdx.x * 256 + threadIdx.x) * 4;
    float4 v = *(const float4*)(in + i);
    ushort4 h, l;
    h.x = rne_bf16(v.x); l.x = rne_bf16(v.x - bf2f(h.x));
    h.y = rne_bf16(v.y); l.y = rne_bf16(v.y - bf2f(h.y));
    h.z = rne_bf16(v.z); l.z = rne_bf16(v.z - bf2f(h.z));
    h.w = rne_bf16(v.w); l.w = rne_bf16(v.w - bf2f(h.w));
    *(ushort4*)(oh + i) = h;
    *(ushort4*)(ol + i) = l;
}

// fp32 [R][C] -> transposed (hi, lo) bf16 [C][R]
__global__ __launch_bounds__(256) void conv_hl_T(
    const float* __restrict__ in, ushort_t* __restrict__ oh, ushort_t* __restrict__ ol,
    int R, int C)
{
    __shared__ float t[32][33];
    const int tx = threadIdx.x & 31, ty = threadIdx.x >> 5;  // 32x8
    const int gr = blockIdx.y * 32, gc = blockIdx.x * 32;
#pragma unroll
    for (int i = 0; i < 4; ++i)
        t[ty + 8 * i][tx] = in[(size_t)(gr + ty + 8 * i) * C + gc + tx];
    __syncthreads();
#pragma unroll
    for (int i = 0; i < 4; ++i) {
        const int oc = gc + ty + 8 * i;
        const float v = t[tx][ty + 8 * i];
        const ushort_t h = rne_bf16(v);
        oh[(size_t)oc * R + gr + tx] = h;
        ol[(size_t)oc * R + gr + tx] = rne_bf16(v - bf2f(h));
    }
}

// Row softmax over 4096 cols; fp32 in, bf16 out.
__global__ __launch_bounds__(256) void softmax_kernel(
    const float* __restrict__ S, ushort_t* __restrict__ P)
{
    __shared__ float red[8];
    const float* p = S + (size_t)blockIdx.x * T_;
    ushort_t* pr = P + (size_t)blockIdx.x * T_;
    const int tid = threadIdx.x;
    const int wid = tid >> 6;
    const int lane = tid & 63;
    float4 v[4];
#pragma unroll
    for (int i = 0; i < 4; ++i) v[i] = ((const float4*)p)[tid + 256 * i];
    float m = -3.0e38f;
#pragma unroll
    for (int i = 0; i < 4; ++i)
        m = fmaxf(m, fmaxf(fmaxf(v[i].x, v[i].y), fmaxf(v[i].z, v[i].w)));
#pragma unroll
    for (int o = 32; o; o >>= 1) m = fmaxf(m, __shfl_xor(m, o));
    if (lane == 0) red[wid] = m;
    __syncthreads();
    m = fmaxf(fmaxf(red[0], red[1]), fmaxf(red[2], red[3]));
    float s = 0.f;
#pragma unroll
    for (int i = 0; i < 4; ++i) {
        v[i].x = __expf(v[i].x - m); v[i].y = __expf(v[i].y - m);
        v[i].z = __expf(v[i].z - m); v[i].w = __expf(v[i].w - m);
        s += v[i].x + v[i].y + v[i].z + v[i].w;
    }
#pragma unroll
    for (int o = 32; o; o >>= 1) s += __shfl_xor(s, o);
    if (lane == 0) red[4 + wid] = s;
    __syncthreads();
    s = red[4] + red[5] + red[6] + red[7];
    const float inv = 1.f / s;
#pragma unroll
    for (int i = 0; i < 4; ++i) {
        ushort4 o4;
        o4.x = rne_bf16(v[i].x * inv); o4.y = rne_bf16(v[i].y * inv);
        o4.z = rne_bf16(v[i].z * inv); o4.w = rne_bf16(v[i].w * inv);
        ((ushort4*)pr)[tid + 256 * i] = o4;
    }
}

// um = (uh+ul) * ov, output as h/l split
__global__ __launch_bounds__(256) void umod_kernel(
    const ushort_t* __restrict__ uh, const ushort_t* __restrict__ ul,
    const float* __restrict__ ov,
    ushort_t* __restrict__ mh, ushort_t* __restrict__ ml)
{
    const size_t i = ((size_t)blockIdx.x * 256 + threadIdx.x) * 4;
    ushort4 h4 = *(const ushort4*)(uh + i);
    ushort4 l4 = *(const ushort4*)(ul + i);
    float4 o = *(const float4*)(ov + i);
    float4 m;
    m.x = (bf2f(h4.x) + bf2f(l4.x)) * o.x;
    m.y = (bf2f(h4.y) + bf2f(l4.y)) * o.y;
    m.z = (bf2f(h4.z) + bf2f(l4.z)) * o.z;
    m.w = (bf2f(h4.w) + bf2f(l4.w)) * o.w;
    ushort4 oh, ol;
    oh.x = rne_bf16(m.x); ol.x = rne_bf16(m.x - bf2f(oh.x));
    oh.y = rne_bf16(m.y); ol.y = rne_bf16(m.y - bf2f(oh.y));
    oh.z = rne_bf16(m.z); ol.z = rne_bf16(m.z - bf2f(oh.z));
    oh.w = rne_bf16(m.w); ol.w = rne_bf16(m.w - bf2f(oh.w));
    *(ushort4*)(mh + i) = oh;
    *(ushort4*)(ml + i) = ol;
}

// ---------------------------------------------------------------------------
// Persistent bidirectional LSTM, v12: 64 WGs/dir x 8 units/WG (2 WGs/CU on
// one XCD). Halves the per-step compute chain vs v11: 64 reg-FMAs + 16
// ds_read_b128 per lane (was 128 + 32 -- ~320 issue-cycles saved). All sync
// machinery identical to v11: one-time mapping consensus -> local-only
// publish, barrier-free steps w/ per-wave private LDS h-stage, batched
// 4x8B sc0 poll, tagged 2-parity dataflow, pace 8 (local) / 25 (agent).
// Lane map: unit j=tid>>5, gate g=(tid>>3)&3, chunk c=tid&7 (64 k each).
// ---------------------------------------------------------------------------
#define NU_ 8
#define PACE_L 8L
#define PACE_A 25L

__global__ __launch_bounds__(256, 1) void lstm_kernel(
    const float* __restrict__ whh_f, const float* __restrict__ whh_b,
    const ushort_t* __restrict__ xg_f, const ushort_t* __restrict__ xg_b,
    float* __restrict__ hf_out, float* __restrict__ hb_out,
    unsigned int* __restrict__ hbuf,   // agent/MALL: [2 dirs][2 parity][512]
    unsigned int* __restrict__ lbuf,   // XCD-local:  [2 dirs][2 parity][512]
    unsigned int* __restrict__ pbuf,   // probes  [2][64] (local)
    unsigned int* __restrict__ vbuf)   // verdicts [2][64] (agent)
{
    const int xcd = blockIdx.x & 7;
    if (xcd >= 2) return;               // helper blocks exit
    const int dir = xcd;
    const int w   = blockIdx.x >> 3;    // 0..63

    __shared__ float sh[4][2][8 * 68]; // per-wave private, parity-dbuffered
    __shared__ int smode;

    const int tid  = threadIdx.x;
    const int wv   = tid >> 6;
    const int lane = tid & 63;
    const int j    = tid >> 5;          // unit 0..7
    const int g    = (tid >> 3) & 3;    // gate 0..3 (i,f,g,o)
    const int c    = tid & 7;           // k-chunk 0..7 (64 elems)
    const int u0   = w * NU_;

    const float* whh = dir ? whh_b : whh_f;
    const ushort_t* xg = dir ? xg_b : xg_f;
    float* hout = dir ? hb_out : hf_out;
    unsigned int* hb = hbuf + dir * 1024;
    unsigned int* lb = lbuf + dir * 1024;

    float wreg[64];
    {
        const float* wr = whh + (size_t)(g * E_ + u0 + j) * E_ + 64 * c;
#pragma unroll
        for (int i = 0; i < 16; ++i)
            *(float4*)&wreg[4 * i] = *(const float4*)(wr + 4 * i);
    }
    for (int i = tid; i < 4 * 2 * 8 * 68; i += 256) ((float*)sh)[i] = 0.f;

    // ---- one-time mapping consensus (all 64 lanes of wave 0 check probes) --
    if (tid == 0)
        __hip_atomic_store(pbuf + dir * 64 + w, 0x5AFE0001u,
                           __ATOMIC_RELAXED, __HIP_MEMORY_SCOPE_WORKGROUP);
    if (tid < 64) {
        bool seen = false;
        {
            const long long t0 = (long long)__builtin_amdgcn_s_memrealtime();
            while (!seen) {
                seen = (load_l2_u32(pbuf + dir * 64 + lane) == 0x5AFE0001u);
                if (!seen &&
                    (long long)__builtin_amdgcn_s_memrealtime() - t0 > 1000) break;
            }
        }
        const int allok = (__ballot(seen) == ~0ull) ? 1 : 0;
        if (lane == 0)
            __hip_atomic_store(vbuf + dir * 64 + w, 0x7E570000u | (unsigned)allok,
                               __ATOMIC_RELAXED, __HIP_MEMORY_SCOPE_AGENT);
        bool vok;
        {
            unsigned int vv = 0, vb = 1u << 22;
            for (;;) {
                vv = __hip_atomic_load(vbuf + dir * 64 + lane, __ATOMIC_RELAXED,
                                       __HIP_MEMORY_SCOPE_AGENT);
                if ((vv >> 16) == 0x7E57u || !--vb) break;
            }
            vok = ((vv >> 16) == 0x7E57u) && (vv & 1u);
        }
        const int consensus = (__ballot(vok) == ~0ull) ? 1 : 0;
        if (lane == 0) smode = consensus;
    }
    __syncthreads();                    // one-time: smode + sh zero-init
    const int mode_local = smode;

    float creg = 0.f;
    const float gsc  = (g == 2) ? 2.f : 1.f;
    const float gmul = (g == 2) ? 2.f : 1.f;
    const float gadd = (g == 2) ? -1.f : 0.f;

    float xv = bf2f(xg[(size_t)(dir ? (T_ - 1) : 0) * G4_ + g * E_ + u0 + j]);
    unsigned int budget = 1u << 23;

    // staging position: u64 m = lane + 64i holds units e=2m,2m+1 ->
    // chunk e>>6, offset e&63 (stride 68 words keeps banks clean)
    const int soff = (lane >> 5) * 68 + (2 * lane & 63);

    long long tpub = (long long)__builtin_amdgcn_s_memrealtime();

    for (int s = 0; s < T_; ++s) {
        const int t = dir ? (T_ - 1 - s) : s;
        float* shw = sh[wv][s & 1];

        if (s > 0) {
            const long long pt = mode_local ? PACE_L : PACE_A;
            while ((long long)__builtin_amdgcn_s_memrealtime() - tpub < pt) {}
            const unsigned int tt = (unsigned int)(s - 1) & 0xFFFFu;
            const unsigned long long* src = (const unsigned long long*)
                ((mode_local ? lb : hb) + ((s - 1) & 1) * 512);
            unsigned long long v0, v1, v2, v3;
            if (mode_local) {
                for (;;) {
                    load_l2_u64x4(src + lane, v0, v1, v2, v3);
                    if (tags8(v0, v1, v2, v3, tt) || !--budget) break;
                }
            } else {
                for (;;) {
                    v0 = __hip_atomic_load(src + lane, __ATOMIC_RELAXED,
                                           __HIP_MEMORY_SCOPE_AGENT);
                    v1 = __hip_atomic_load(src + lane + 64, __ATOMIC_RELAXED,
                                           __HIP_MEMORY_SCOPE_AGENT);
                    v2 = __hip_atomic_load(src + lane + 128, __ATOMIC_RELAXED,
                                           __HIP_MEMORY_SCOPE_AGENT);
                    v3 = __hip_atomic_load(src + lane + 192, __ATOMIC_RELAXED,
                                           __HIP_MEMORY_SCOPE_AGENT);
                    if (tags8(v0, v1, v2, v3, tt) || !--budget) break;
                }
            }
            float2 h0, h1, h2, h3;
            h0.x = __uint_as_float((unsigned int)v0 << 16);
            h0.y = __uint_as_float((unsigned int)(v0 >> 32) << 16);
            h1.x = __uint_as_float((unsigned int)v1 << 16);
            h1.y = __uint_as_float((unsigned int)(v1 >> 32) << 16);
            h2.x = __uint_as_float((unsigned int)v2 << 16);
            h2.y = __uint_as_float((unsigned int)(v2 >> 32) << 16);
            h3.x = __uint_as_float((unsigned int)v3 << 16);
            h3.y = __uint_as_float((unsigned int)(v3 >> 32) << 16);
            *(float2*)&shw[soff]       = h0;   // i=0: chunks 0/1
            *(float2*)&shw[soff + 136] = h1;   // i=1: chunks 2/3
            *(float2*)&shw[soff + 272] = h2;   // i=2: chunks 4/5
            *(float2*)&shw[soff + 408] = h3;   // i=3: chunks 6/7
            asm volatile("s_waitcnt lgkmcnt(0)" ::: "memory");  // intra-wave order
        }

        // matvec: 64 reg-weight FMAs, 4 independent accumulators
        const float* hc = &shw[68 * c];
        float sx = 0.f, sy = 0.f, sz = 0.f, sw = 0.f;
#pragma unroll
        for (int i = 0; i < 16; ++i) {
            const float4 h4 = *(const float4*)&hc[4 * i];
            sx = fmaf(wreg[4 * i + 0], h4.x, sx);
            sy = fmaf(wreg[4 * i + 1], h4.y, sy);
            sz = fmaf(wreg[4 * i + 2], h4.z, sz);
            sw = fmaf(wreg[4 * i + 3], h4.w, sw);
        }
        float sum = (sx + sy) + (sz + sw);
        // reduce across the 8 chunk-lanes of this gate group
        sum += __shfl_xor(sum, 1);
        sum += __shfl_xor(sum, 2);
        sum += __shfl_xor(sum, 4);

        const float xx = (sum + xv) * gsc;
        const float rr = __builtin_amdgcn_rcpf(1.f + __expf(-xx));
        const float val = fmaf(rr, gmul, gadd);

        // gather the 4 gates of this lane's unit (within-wave shuffles)
        const int base = (lane & 32) + c;
        const float iv = __shfl(val, base);
        const float fv = __shfl(val, base + 8);
        const float gv = __shfl(val, base + 16);
        const float ov = __shfl(val, base + 24);
        creg = fmaf(fv, creg, iv * gv);      // redundant across the 32 unit-lanes
        const float th = fmaf(2.f, __builtin_amdgcn_rcpf(1.f + __expf(-2.f * creg)), -1.f);
        const float h = ov * th;

        if ((tid & 31) == 0) {
            const unsigned int ub = __float_as_uint(h);
            const unsigned int b16 = (ub + 0x7FFFu + ((ub >> 16) & 1u)) >> 16;
            const unsigned int pkt = (((unsigned int)s & 0xFFFFu) << 16) | b16;
            if (mode_local) {
                __hip_atomic_store(lb + (s & 1) * 512 + u0 + j, pkt,
                                   __ATOMIC_RELAXED, __HIP_MEMORY_SCOPE_WORKGROUP);
            } else {
                __hip_atomic_store(hb + (s & 1) * 512 + u0 + j, pkt,
                                   __ATOMIC_RELAXED, __HIP_MEMORY_SCOPE_AGENT);
            }
            hout[(size_t)t * E_ + u0 + j] = h;
        }
        tpub = (long long)__builtin_amdgcn_s_memrealtime();

        if (s + 1 < T_)
            xv = bf2f(xg[(size_t)(dir ? (T_ - 2 - s) : (s + 1)) * G4_ + g * E_ + u0 + j]);
    }
}

// score[t] = dot(hf[t], fw[0:512]) + dot(hb[t], fw[512:1024]) + fb
__global__ __launch_bounds__(256) void final_kernel(
    const float* __restrict__ hf, const float* __restrict__ hb,
    const float* __restrict__ fw, const float* __restrict__ fb,
    float* __restrict__ out)
{
    const int t = blockIdx.x * 4 + (threadIdx.x >> 6);
    const int lane = threadIdx.x & 63;
    float s = 0.f;
#pragma unroll
    for (int i = 0; i < 8; ++i) {
        const int e = lane + 64 * i;
        s += hf[(size_t)t * E_ + e] * fw[e];
    }
#pragma unroll
    for (int i = 0; i < 8; ++i) {
        const int e = lane + 64 * i;
        s += hb[(size_t)t * E_ + e] * fw[E_ + e];
    }
#pragma unroll
    for (int o = 32; o; o >>= 1) s += __shfl_xor(s, o);
    if (lane == 0) out[t] = s + fb[0];
}

// ---------------------------------------------------------------------------
// Workspace layout (MiB offsets; peak ~114 MiB):
//  uh@0-4 ul@4-8 | b@8-16 | xh@16-24 xl@24-32 | ATh@32 ATl@33 BTh@34 BTl@35
//  UTh@36 UTl@37 | ah@38-42 al@42-46 | bTh@46-50 bTl@50-54 | S@56-120
//  Ph@8-40 | ov@56-64 umh@64-68 uml@68-72 wfh@72 wfl@74 wbh@76 wbl@78
//  xfg@80-96 xbg@96-112 | hf@0-8 hb@8-16
//  hbuf@112 lbuf@112+8K pbuf@112+16K vbuf@112+20K
// ---------------------------------------------------------------------------
extern "C" void kernel_launch(void* const* d_in, const int* in_sizes, int n_in,
                              void* d_out, int out_size, void* d_ws, size_t ws_size,
                              hipStream_t stream)
{
    const float* x     = (const float*)d_in[0];
    const float* Amat  = (const float*)d_in[1];
    const float* Bmat  = (const float*)d_in[2];
    const float* Umat  = (const float*)d_in[3];
    const float* wih_f = (const float*)d_in[4];
    const float* whh_f = (const float*)d_in[5];
    const float* bih_f = (const float*)d_in[6];
    const float* bhh_f = (const float*)d_in[7];
    const float* wih_b = (const float*)d_in[8];
    const float* whh_b = (const float*)d_in[9];
    const float* bih_b = (const float*)d_in[10];
    const float* bhh_b = (const float*)d_in[11];
    const float* fw    = (const float*)d_in[12];
    const float* fb    = (const float*)d_in[13];
    float* out = (float*)d_out;
    char* wsb = (char*)d_ws;
    const size_t MB = 1048576ull;

    ushort_t* uh  = (ushort_t*)(wsb + 0 * MB);
    ushort_t* ul  = (ushort_t*)(wsb + 4 * MB);
    float*    bfp = (float*)   (wsb + 8 * MB);
    ushort_t* xh  = (ushort_t*)(wsb + 16 * MB);
    ushort_t* xl  = (ushort_t*)(wsb + 24 * MB);
    ushort_t* ATh = (ushort_t*)(wsb + 32 * MB);
    ushort_t* ATl = (ushort_t*)(wsb + 33 * MB);
    ushort_t* BTh = (ushort_t*)(wsb + 34 * MB);
    ushort_t* BTl = (ushort_t*)(wsb + 35 * MB);
    ushort_t* UTh = (ushort_t*)(wsb + 36 * MB);
    ushort_t* UTl = (ushort_t*)(wsb + 37 * MB);
    ushort_t* ah  = (ushort_t*)(wsb + 38 * MB);
    ushort_t* al  = (ushort_t*)(wsb + 42 * MB);
    ushort_t* bTh = (ushort_t*)(wsb + 46 * MB);
    ushort_t* bTl = (ushort_t*)(wsb + 50 * MB);
    float*    S_  = (float*)   (wsb + 56 * MB);
    ushort_t* Ph  = (ushort_t*)(wsb + 8 * MB);
    float*    ov_ = (float*)   (wsb + 56 * MB);
    ushort_t* umh = (ushort_t*)(wsb + 64 * MB);
    ushort_t* uml = (ushort_t*)(wsb + 68 * MB);
    ushort_t* wfh = (ushort_t*)(wsb + 72 * MB);
    ushort_t* wfl = (ushort_t*)(wsb + 74 * MB);
    ushort_t* wbh = (ushort_t*)(wsb + 76 * MB);
    ushort_t* wbl = (ushort_t*)(wsb + 78 * MB);
    ushort_t* xfg = (ushort_t*)(wsb + 80 * MB);
    ushort_t* xbg = (ushort_t*)(wsb + 96 * MB);
    float*    hf_ = (float*)   (wsb + 0 * MB);
    float*    hb_ = (float*)   (wsb + 8 * MB);
    unsigned int* hbuf_ = (unsigned int*)(wsb + 112 * MB);
    unsigned int* lbuf_ = (unsigned int*)(wsb + 112 * MB + 8192);
    unsigned int* pbuf_ = (unsigned int*)(wsb + 112 * MB + 16384);
    unsigned int* vbuf_ = (unsigned int*)(wsb + 112 * MB + 20480);

    dim3 blk(256);

    conv_hl<<<dim3(4096), blk, 0, stream>>>(x, xh, xl);
    conv_hl_T<<<dim3(16, 32), blk, 0, stream>>>(Amat, ATh, ATl, 1024, 512);
    conv_hl_T<<<dim3(16, 32), blk, 0, stream>>>(Bmat, BTh, BTl, 1024, 512);
    conv_hl_T<<<dim3(16, 32), blk, 0, stream>>>(Umat, UTh, UTl, 1024, 512);
    mfma_gemm<<<dim3(4, 32), blk, 0, stream>>>(xh, xl, ATh, ATl, nullptr, ah, al,
                                               T_, E_, IN_, 2, nullptr, nullptr);
    mfma_gemm<<<dim3(4, 32), blk, 0, stream>>>(xh, xl, BTh, BTl, bfp, nullptr, nullptr,
                                               T_, E_, IN_, 2, nullptr, nullptr);
    mfma_gemm<<<dim3(4, 32), blk, 0, stream>>>(xh, xl, UTh, UTl, nullptr, uh, ul,
                                               T_, E_, IN_, 2, nullptr, nullptr);
    mfma_gemm<<<dim3(32, 32), blk, 0, stream>>>(uh, ul, ah, al, S_, nullptr, nullptr,
                                                T_, T_, E_, 2, nullptr, nullptr);
    conv_hl_T<<<dim3(16, 128), blk, 0, stream>>>(bfp, bTh, bTl, 4096, 512);
    softmax_kernel<<<dim3(T_), blk, 0, stream>>>(S_, Ph);
    mfma_gemm<<<dim3(4, 32), blk, 0, stream>>>(Ph, nullptr, bTh, bTl, ov_, nullptr, nullptr,
                                               T_, E_, T_, 1, nullptr, nullptr);
    umod_kernel<<<dim3(2048), blk, 0, stream>>>(uh, ul, ov_, umh, uml);
    conv_hl<<<dim3(1024), blk, 0, stream>>>(wih_f, wfh, wfl);
    conv_hl<<<dim3(1024), blk, 0, stream>>>(wih_b, wbh, wbl);
    mfma_gemm<<<dim3(16, 32), blk, 0, stream>>>(umh, uml, wfh, wfl, nullptr, xfg, nullptr,
                                                T_, G4_, E_, 2, bih_f, bhh_f);
    mfma_gemm<<<dim3(16, 32), blk, 0, stream>>>(umh, uml, wbh, wbl, nullptr, xbg, nullptr,
                                                T_, G4_, E_, 2, bih_b, bhh_b);
    lstm_kernel<<<dim3(512), blk, 0, stream>>>(whh_f, whh_b, xfg, xbg, hf_, hb_,
                                               hbuf_, lbuf_, pbuf_, vbuf_);
    final_kernel<<<dim3(1024), blk, 0, stream>>>(hf_, hb_, fw, fb, out);
}